// Round 3
// baseline (273.054 us; speedup 1.0000x reference)
//
#include <hip/hip_runtime.h>

#define EPS 1e-5f

typedef unsigned short ushort;
typedef unsigned int uint;
typedef __attribute__((ext_vector_type(8)))  short  short8;
typedef __attribute__((ext_vector_type(8)))  ushort ushort8;
typedef __attribute__((ext_vector_type(16))) float  f32x16;

// bf16 round-to-nearest-even split helpers (bit tricks; inputs are normal floats)
__device__ __forceinline__ ushort f2bf(float v) {
    uint b = __float_as_uint(v);
    return (ushort)((b + 0x7fffu + ((b >> 16) & 1u)) >> 16);
}
__device__ __forceinline__ float bf2f(ushort u) {
    return __uint_as_float(((uint)u) << 16);
}

// ---- prep: W[k][c][d] fp32 -> Wt_hi/Wt_lo[k][d][c] bf16 (transposed, split) ----
__global__ void prep_w(const float* __restrict__ W,
                       ushort* __restrict__ hi, ushort* __restrict__ lo) {
    int e = blockIdx.x * 256 + threadIdx.x;     // e over 9*64*64
    int c = e & 63, d = (e >> 6) & 63, k = e >> 12;
    float v = W[(k << 12) + (c << 6) + d];
    ushort h = f2bf(v);
    hi[e] = h;
    lo[e] = f2bf(v - bf2f(h));
}

// out[n,d] = epilogue( sum_k sum_c f[nbr[n,k],c] * W[k,c,d] )
// Block: 64 rows x 64 cols, 256 threads = 4 waves in 2x2 grid, each wave a
// 32x32 output tile via mfma_f32_32x32x16_bf16 with 3-term hi/lo fp32 emulation.
// LDS tiles padded to 72 cols (144B row stride) -> conflict-free b128 reads.
template<bool SECOND>
__global__ __launch_bounds__(256, 4) void subm_conv_mfma(
    const float*  __restrict__ f,      // features to gather [N,64] fp32
    const int*    __restrict__ nbr,    // [N,9]
    const ushort* __restrict__ Wth,    // [9][64][64] bf16 hi, already [k][d][c]
    const ushort* __restrict__ Wtl,    // [9][64][64] bf16 lo
    const float*  __restrict__ gamma,
    const float*  __restrict__ beta,
    const float*  __restrict__ rmean,
    const float*  __restrict__ rvar,
    const float*  __restrict__ resid,  // x, only when SECOND
    float* __restrict__ out)           // [N,64] fp32
{
    __shared__ __align__(16) ushort Ah[64][72];
    __shared__ __align__(16) ushort Al[64][72];
    __shared__ __align__(16) ushort Bh[64][72];
    __shared__ __align__(16) ushort Bl[64][72];

    const int t    = threadIdx.x;
    const int lane = t & 63;
    const int w    = t >> 6;            // wave 0..3
    const int wr   = (w >> 1) << 5;     // wave row offset (0/32)
    const int wc   = (w & 1) << 5;      // wave col offset (0/32)
    const int row0 = blockIdx.x << 6;

    const int sr = t >> 2;              // staging row / d  (0..63)
    const int sc = (t & 3) << 4;        // staging c offset (0,16,32,48)

    f32x16 acc = 0.f;

    // fragment addresses (invariant over k)
    const int rA   = wr + (lane & 31);
    const int rB   = wc + (lane & 31);
    const int koff = (lane >> 5) << 3;  // 0 or 8

    for (int k = 0; k < 9; ++k) {
        // ---- global loads for this k ----
        const int m = nbr[(row0 + sr) * 9 + k];
        const float4* ap = (const float4*)(f + (size_t)m * 64 + sc);
        float4 v0 = ap[0], v1 = ap[1], v2 = ap[2], v3 = ap[3];

        const int woff = (k << 12) + (sr << 6) + sc;
        const uint4* whp = (const uint4*)(Wth + woff);
        const uint4* wlp = (const uint4*)(Wtl + woff);
        uint4 wh0 = whp[0], wh1 = whp[1];
        uint4 wl0 = wlp[0], wl1 = wlp[1];

        // ---- convert features to bf16 hi/lo (register-only) ----
        float a0[8] = {v0.x,v0.y,v0.z,v0.w, v1.x,v1.y,v1.z,v1.w};
        float a1[8] = {v2.x,v2.y,v2.z,v2.w, v3.x,v3.y,v3.z,v3.w};
        ushort8 h0, l0, h1, l1;
        #pragma unroll
        for (int j = 0; j < 8; ++j) {
            ushort h = f2bf(a0[j]);
            h0[j] = h; l0[j] = f2bf(a0[j] - bf2f(h));
            ushort g = f2bf(a1[j]);
            h1[j] = g; l1[j] = f2bf(a1[j] - bf2f(g));
        }

        __syncthreads();   // previous iteration's LDS reads complete

        *(ushort8*)&Ah[sr][sc]     = h0;
        *(ushort8*)&Al[sr][sc]     = l0;
        *(ushort8*)&Ah[sr][sc + 8] = h1;
        *(ushort8*)&Al[sr][sc + 8] = l1;
        *(uint4*)&Bh[sr][sc]       = wh0;
        *(uint4*)&Bh[sr][sc + 8]   = wh1;
        *(uint4*)&Bl[sr][sc]       = wl0;
        *(uint4*)&Bl[sr][sc + 8]   = wl1;

        __syncthreads();

        // ---- 4 K-chunks of 16, 3 MFMAs each (hi*hi, hi*lo, lo*hi) ----
        #pragma unroll
        for (int h = 0; h < 4; ++h) {
            const int co = (h << 4) + koff;
            short8 fah = *(const short8*)&Ah[rA][co];
            short8 fal = *(const short8*)&Al[rA][co];
            short8 fbh = *(const short8*)&Bh[rB][co];
            short8 fbl = *(const short8*)&Bl[rB][co];
            acc = __builtin_amdgcn_mfma_f32_32x32x16_bf16(fah, fbh, acc, 0, 0, 0);
            acc = __builtin_amdgcn_mfma_f32_32x32x16_bf16(fah, fbl, acc, 0, 0, 0);
            acc = __builtin_amdgcn_mfma_f32_32x32x16_bf16(fal, fbh, acc, 0, 0, 0);
        }
    }

    // ---- epilogue: BN (+ residual) + ReLU ----
    // C/D layout (verified): col = lane&31, row = (reg&3) + 8*(reg>>2) + 4*(lane>>5)
    const int d   = wc + (lane & 31);
    const float iv  = gamma[d] * rsqrtf(rvar[d] + EPS);
    const float add = beta[d] - rmean[d] * iv;
    const int rb  = row0 + wr + ((lane >> 5) << 2);
    #pragma unroll
    for (int i = 0; i < 16; ++i) {
        const int n = rb + (i & 3) + ((i >> 2) << 3);
        float val = fmaf(acc[i], iv, add);
        if (SECOND) val += resid[(size_t)n * 64 + d];
        out[(size_t)n * 64 + d] = fmaxf(val, 0.f);
    }
}

extern "C" void kernel_launch(void* const* d_in, const int* in_sizes, int n_in,
                              void* d_out, int out_size, void* d_ws, size_t ws_size,
                              hipStream_t stream) {
    const float* x   = (const float*)d_in[0];
    const int*   nbr = (const int*)  d_in[1];
    const float* W1  = (const float*)d_in[2];
    const float* g1  = (const float*)d_in[3];
    const float* b1  = (const float*)d_in[4];
    const float* rm1 = (const float*)d_in[5];
    const float* rv1 = (const float*)d_in[6];
    const float* W2  = (const float*)d_in[7];
    const float* g2  = (const float*)d_in[8];
    const float* b2  = (const float*)d_in[9];
    const float* rm2 = (const float*)d_in[10];
    const float* rv2 = (const float*)d_in[11];

    const int N    = in_sizes[0] / 64;   // 200000
    const int grid = N / 64;             // 3125 exact

    // ws layout: [mid fp32 N*64][W1t_hi][W1t_lo][W2t_hi][W2t_lo]
    char* ws = (char*)d_ws;
    float*  mid  = (float*)ws;                         ws += (size_t)N * 64 * 4;
    ushort* W1h  = (ushort*)ws;                        ws += 9 * 64 * 64 * 2;
    ushort* W1l  = (ushort*)ws;                        ws += 9 * 64 * 64 * 2;
    ushort* W2h  = (ushort*)ws;                        ws += 9 * 64 * 64 * 2;
    ushort* W2l  = (ushort*)ws;

    prep_w<<<144, 256, 0, stream>>>(W1, W1h, W1l);
    prep_w<<<144, 256, 0, stream>>>(W2, W2h, W2l);

    subm_conv_mfma<false><<<grid, 256, 0, stream>>>(
        x,   nbr, W1h, W1l, g1, b1, rm1, rv1, nullptr, mid);
    subm_conv_mfma<true ><<<grid, 256, 0, stream>>>(
        mid, nbr, W2h, W2l, g2, b2, rm2, rv2, x, (float*)d_out);
}